// Round 1
// baseline (128.928 us; speedup 1.0000x reference)
//
#include <hip/hip_runtime.h>
#include <hip/hip_bf16.h>
#include <stdint.h>

// Problem constants: B=1, N=2048, D=1024, h=16, e=64
#define NTOK 2048
#define DMODEL 1024
#define NH 16
#define EH 64
#define NCH 32     // chunks of 64 tokens
#define TCH 64
#define EPSV 1e-6f

typedef __attribute__((ext_vector_type(8))) short bf16x8;
typedef __attribute__((ext_vector_type(4))) float f32x4;

__device__ __forceinline__ unsigned short f2bf(float f) {
  unsigned u = __float_as_uint(f);
  u += 0x7fffu + ((u >> 16) & 1u);   // RNE
  return (unsigned short)(u >> 16);
}

// ---- x (2048x1024 f32) -> bf16 ----
__global__ __launch_bounds__(256) void k_convert_x(const float* __restrict__ x,
                                                   unsigned short* __restrict__ xb) {
  int i = (blockIdx.x * 256 + threadIdx.x) * 4;
  float4 v = *(const float4*)(x + i);
  ushort4 o = { f2bf(v.x), f2bf(v.y), f2bf(v.z), f2bf(v.w) };
  *(ushort4*)(xb + i) = o;
}

// ---- W (1024x3072 f32) -> Wt (3072x1024 bf16) ----
__global__ __launch_bounds__(256) void k_transpose_w(const float* __restrict__ W,
                                                     unsigned short* __restrict__ Wt) {
  __shared__ float tile[32][33];
  int tx = threadIdx.x & 31, ty = threadIdx.x >> 5;
  int c0 = blockIdx.x * 32;   // W col
  int r0 = blockIdx.y * 32;   // W row
#pragma unroll
  for (int j = 0; j < 32; j += 8)
    tile[ty + j][tx] = W[(size_t)(r0 + ty + j) * 3072 + c0 + tx];
  __syncthreads();
#pragma unroll
  for (int j = 0; j < 32; j += 8)
    Wt[(size_t)(c0 + ty + j) * 1024 + r0 + tx] = f2bf(tile[tx][ty + j]);
}

// ---- qvk = xb @ Wt^T + b : 2048x3072 fp32, 128x128 tile, BK=32 ----
__global__ __launch_bounds__(256) void k_gemm(const unsigned short* __restrict__ xb,
                                              const unsigned short* __restrict__ wt,
                                              const float* __restrict__ bias,
                                              float* __restrict__ qvk) {
  __shared__ __align__(16) unsigned short As[128][32];
  __shared__ __align__(16) unsigned short Bs[128][32];
  const int t = threadIdx.x;
  const int lane = t & 63;
  const int wave = t >> 6;
  const int wr = wave >> 1, wc = wave & 1;
  const int rowBase = blockIdx.y * 128;
  const int colBase = blockIdx.x * 128;
  const int srow = t >> 2;
  const int scol = (t & 3) * 8;
  const unsigned short* ag = xb + (size_t)(rowBase + srow) * 1024 + scol;
  const unsigned short* bg = wt + (size_t)(colBase + srow) * 1024 + scol;
  unsigned short* al = &As[srow][scol];
  unsigned short* bl = &Bs[srow][scol];
  f32x4 acc[4][4] = {};
  const int fr = lane & 15;
  const int fk = (lane >> 4) * 8;
  for (int k0 = 0; k0 < 1024; k0 += 32) {
    __builtin_amdgcn_global_load_lds((const __attribute__((address_space(1))) void*)(ag + k0),
                                     (__attribute__((address_space(3))) void*)al, 16, 0, 0);
    __builtin_amdgcn_global_load_lds((const __attribute__((address_space(1))) void*)(ag + 64 * 1024 + k0),
                                     (__attribute__((address_space(3))) void*)(al + 64 * 32), 16, 0, 0);
    __builtin_amdgcn_global_load_lds((const __attribute__((address_space(1))) void*)(bg + k0),
                                     (__attribute__((address_space(3))) void*)bl, 16, 0, 0);
    __builtin_amdgcn_global_load_lds((const __attribute__((address_space(1))) void*)(bg + 64 * 1024 + k0),
                                     (__attribute__((address_space(3))) void*)(bl + 64 * 32), 16, 0, 0);
    __syncthreads();
    bf16x8 af[4], bfr[4];
#pragma unroll
    for (int m = 0; m < 4; ++m)
      af[m] = *(const bf16x8*)&As[wr * 64 + m * 16 + fr][fk];
#pragma unroll
    for (int n = 0; n < 4; ++n)
      bfr[n] = *(const bf16x8*)&Bs[wc * 64 + n * 16 + fr][fk];
#pragma unroll
    for (int m = 0; m < 4; ++m)
#pragma unroll
      for (int n = 0; n < 4; ++n)
        acc[m][n] = __builtin_amdgcn_mfma_f32_16x16x32_bf16(af[m], bfr[n], acc[m][n], 0, 0, 0);
    __syncthreads();
  }
  const int orow = (lane >> 4) * 4;
  const int ocol = lane & 15;
#pragma unroll
  for (int n = 0; n < 4; ++n) {
    int col = colBase + wc * 64 + n * 16 + ocol;
    float bv = bias[col];
#pragma unroll
    for (int m = 0; m < 4; ++m) {
      int row = rowBase + wr * 64 + m * 16 + orow;
#pragma unroll
      for (int i = 0; i < 4; ++i)
        qvk[(size_t)(row + i) * 3072 + col] = acc[m][n][i] + bv;
    }
  }
}

// ---- split q,v,k -> head-major; q=softmax*e^-0.5, k=exp(k) ----
__global__ __launch_bounds__(256) void k_prep(const float* __restrict__ qvk,
                                              float* __restrict__ qh,
                                              float* __restrict__ kh,
                                              float* __restrict__ vh) {
  int task = blockIdx.x * 4 + (threadIdx.x >> 6);  // (n,h) pair
  int lane = threadIdx.x & 63;
  int n = task >> 4;
  int h = task & 15;
  const float* row = qvk + (size_t)n * 3072;
  float q = row[h * 64 + lane];
  float v = row[1024 + h * 64 + lane];
  float k = row[2048 + h * 64 + lane];
  float m = q;
#pragma unroll
  for (int off = 32; off >= 1; off >>= 1) m = fmaxf(m, __shfl_xor(m, off));
  float e = __expf(q - m);
  float s = e;
#pragma unroll
  for (int off = 32; off >= 1; off >>= 1) s += __shfl_xor(s, off);
  size_t idx = ((size_t)h * NTOK + n) * 64 + lane;
  qh[idx] = e / s * 0.125f;   // * e^{-1/2} = 1/8
  kh[idx] = __expf(k);
  vh[idx] = v;
}

// ---- per-(head,chunk) sums: S_c = sum k v^T (64x64), z_c = sum k ----
__global__ __launch_bounds__(256) void k_chunk_sums(const float* __restrict__ kh,
                                                    const float* __restrict__ vh,
                                                    float* __restrict__ Sc,
                                                    float* __restrict__ zc) {
  int h = blockIdx.x >> 5;
  int c = blockIdx.x & 31;
  int t = threadIdx.x;
  int lane = t & 63, wave = t >> 6;
  int dblk = t >> 4, eblk = t & 15;
  __shared__ float ks[16][64], vs[16][64];
  float S[4][4] = {{0}};
  float z = 0.f;
  const float* kb = kh + ((size_t)h * NTOK + c * 64) * 64;
  const float* vb = vh + ((size_t)h * NTOK + c * 64) * 64;
  int sr = t >> 4, sc = (t & 15) * 4;
  for (int b = 0; b < 4; ++b) {
    __syncthreads();
    *(float4*)&ks[sr][sc] = *(const float4*)&kb[(b * 16 + sr) * 64 + sc];
    *(float4*)&vs[sr][sc] = *(const float4*)&vb[(b * 16 + sr) * 64 + sc];
    __syncthreads();
    for (int i = 0; i < 16; ++i) {
      float4 kv = *(float4*)&ks[i][dblk * 4];
      float4 vv = *(float4*)&vs[i][eblk * 4];
      float kj[4] = {kv.x, kv.y, kv.z, kv.w};
      float vl[4] = {vv.x, vv.y, vv.z, vv.w};
#pragma unroll
      for (int j = 0; j < 4; ++j)
#pragma unroll
        for (int l = 0; l < 4; ++l)
          S[j][l] = fmaf(kj[j], vl[l], S[j][l]);
      if (wave == 0) z += ks[i][lane];
    }
  }
  float* so = Sc + (size_t)(h * NCH + c) * 4096;
#pragma unroll
  for (int j = 0; j < 4; ++j) {
    float4 o = {S[j][0], S[j][1], S[j][2], S[j][3]};
    *(float4*)&so[(dblk * 4 + j) * 64 + eblk * 4] = o;
  }
  if (wave == 0) zc[(size_t)(h * NCH + c) * 64 + lane] = z;
}

// ---- per-head exclusive scan over chunks (in place) ----
__global__ __launch_bounds__(256) void k_scan(float* __restrict__ Sc, float* __restrict__ zc) {
  int h = blockIdx.x;
  int t = threadIdx.x;
  float4 run[4] = {};
  for (int c = 0; c < NCH; ++c) {
    float* p = Sc + (size_t)(h * NCH + c) * 4096 + t * 16;
#pragma unroll
    for (int j = 0; j < 4; ++j) {
      float4 v = *(float4*)(p + j * 4);
      *(float4*)(p + j * 4) = run[j];
      run[j].x += v.x; run[j].y += v.y; run[j].z += v.z; run[j].w += v.w;
    }
  }
  if (t < 64) {
    float zr = 0.f;
    for (int c = 0; c < NCH; ++c) {
      float* p = zc + (size_t)(h * NCH + c) * 64 + t;
      float v = *p; *p = zr; zr += v;
    }
  }
}

// ---- output pass: sequential in-chunk scan, S in registers; fused denom + layout ----
__global__ __launch_bounds__(256) void k_attn_out(const float* __restrict__ qh,
                                                  const float* __restrict__ kh,
                                                  const float* __restrict__ vh,
                                                  const float* __restrict__ Sp,
                                                  const float* __restrict__ zp,
                                                  float* __restrict__ out) {
  int h = blockIdx.x >> 5;
  int c = blockIdx.x & 31;
  int t = threadIdx.x;
  int lane = t & 63, wave = t >> 6;
  int dblk = t >> 4, eblk = t & 15;
  __shared__ float qs[16][64], ks[16][64], vs[16][64];
  __shared__ float part[16][64];
  float S[4][4];
  const float* sp = Sp + (size_t)(h * NCH + c) * 4096;
#pragma unroll
  for (int j = 0; j < 4; ++j) {
    float4 v = *(const float4*)&sp[(dblk * 4 + j) * 64 + eblk * 4];
    S[j][0] = v.x; S[j][1] = v.y; S[j][2] = v.z; S[j][3] = v.w;
  }
  float z = (wave == 0) ? zp[(size_t)(h * NCH + c) * 64 + lane] : 0.f;
  const size_t rb = ((size_t)h * NTOK + c * 64) * 64;
  int sr = t >> 4, scc = (t & 15) * 4;
  for (int b = 0; b < 4; ++b) {
    __syncthreads();
    *(float4*)&qs[sr][scc] = *(const float4*)&qh[rb + (b * 16 + sr) * 64 + scc];
    *(float4*)&ks[sr][scc] = *(const float4*)&kh[rb + (b * 16 + sr) * 64 + scc];
    *(float4*)&vs[sr][scc] = *(const float4*)&vh[rb + (b * 16 + sr) * 64 + scc];
    __syncthreads();
    for (int i = 0; i < 16; ++i) {
      float4 kv = *(float4*)&ks[i][dblk * 4];
      float4 vv = *(float4*)&vs[i][eblk * 4];
      float kj[4] = {kv.x, kv.y, kv.z, kv.w};
      float vl[4] = {vv.x, vv.y, vv.z, vv.w};
#pragma unroll
      for (int j = 0; j < 4; ++j)
#pragma unroll
        for (int l = 0; l < 4; ++l)
          S[j][l] = fmaf(kj[j], vl[l], S[j][l]);   // inclusive state update
      float4 qv = *(float4*)&qs[i][dblk * 4];
      float p[4];
#pragma unroll
      for (int l = 0; l < 4; ++l)
        p[l] = qv.x * S[0][l] + qv.y * S[1][l] + qv.z * S[2][l] + qv.w * S[3][l];
      *(float4*)&part[dblk][eblk * 4] = make_float4(p[0], p[1], p[2], p[3]);
      __syncthreads();
      if (wave == 0) {
        z += ks[i][lane];
        float dv = qs[i][lane] * (z + EPSV);
#pragma unroll
        for (int off = 32; off >= 1; off >>= 1) dv += __shfl_xor(dv, off);
        float o = 0.f;
#pragma unroll
        for (int db = 0; db < 16; ++db) o += part[db][lane];
        int n = c * 64 + b * 16 + i;
        out[(size_t)n * 1024 + h * 64 + lane] = o / dv;
      }
      __syncthreads();
    }
  }
}

extern "C" void kernel_launch(void* const* d_in, const int* in_sizes, int n_in,
                              void* d_out, int out_size, void* d_ws, size_t ws_size,
                              hipStream_t stream) {
  (void)in_sizes; (void)n_in; (void)out_size; (void)ws_size;
  const float* x = (const float*)d_in[0];
  const float* W = (const float*)d_in[1];
  const float* b = (const float*)d_in[2];
  char* ws = (char*)d_ws;

  unsigned short* xb = (unsigned short*)(ws + 0);            // 4 MB  [0, 4,194,304)
  unsigned short* Wt = (unsigned short*)(ws + 4194304);      // 6 MB  [4,194,304, 10,485,760)
  float* qvk = (float*)(ws + 10485760);                      // 24 MB [10,485,760, 35,651,584)
  float* qh  = (float*)(ws + 0);                             // 8 MB overlay (xb/Wt dead after GEMM)
  float* kh  = (float*)(ws + 35651584);                      // 8 MB
  float* vh  = (float*)(ws + 44040192);                      // 8 MB
  float* Sc  = (float*)(ws + 52428800);                      // 8 MB (becomes exclusive prefix in place)
  float* zc  = (float*)(ws + 60817408);                      // 128 KB

  k_convert_x<<<dim3(2048), dim3(256), 0, stream>>>(x, xb);
  k_transpose_w<<<dim3(96, 32), dim3(256), 0, stream>>>(W, Wt);
  k_gemm<<<dim3(24, 16), dim3(256), 0, stream>>>(xb, Wt, b, qvk);
  k_prep<<<dim3(8192), dim3(256), 0, stream>>>(qvk, qh, kh, vh);
  k_chunk_sums<<<dim3(512), dim3(256), 0, stream>>>(kh, vh, Sc, zc);
  k_scan<<<dim3(16), dim3(256), 0, stream>>>(Sc, zc);
  k_attn_out<<<dim3(512), dim3(256), 0, stream>>>(qh, kh, vh, Sc, zc, (float*)d_out);
}

// Round 2
// 61.347 us; speedup vs baseline: 2.1016x; 2.1016x over previous
//
#include <hip/hip_runtime.h>
#include <stdint.h>

// B=1, N=2048, D=1024, h=16, e=64; chunks of 64 tokens -> 32 chunks/head
#define NTOK 2048
#define NCH 32

typedef __attribute__((ext_vector_type(8))) short bf16x8;
typedef __attribute__((ext_vector_type(8))) unsigned short ushort8v;
typedef __attribute__((ext_vector_type(4))) float f32x4;

__device__ __forceinline__ unsigned short f2bf(float f) {
  unsigned u = __float_as_uint(f);
  u += 0x7fffu + ((u >> 16) & 1u);   // RNE
  return (unsigned short)(u >> 16);
}
__device__ __forceinline__ float bf2f(unsigned short s) {
  return __uint_as_float(((unsigned)s) << 16);
}

// ---- x (2048x1024 f32) -> bf16 ----
__global__ __launch_bounds__(256) void k_convert_x(const float* __restrict__ x,
                                                   unsigned short* __restrict__ xb) {
  int i = (blockIdx.x * 256 + threadIdx.x) * 4;
  float4 v = *(const float4*)(x + i);
  ushort4 o = { f2bf(v.x), f2bf(v.y), f2bf(v.z), f2bf(v.w) };
  *(ushort4*)(xb + i) = o;
}

// ---- W (1024x3072 f32) -> Wt (3072x1024 bf16) ----
__global__ __launch_bounds__(256) void k_transpose_w(const float* __restrict__ W,
                                                     unsigned short* __restrict__ Wt) {
  __shared__ float tile[32][33];
  int tx = threadIdx.x & 31, ty = threadIdx.x >> 5;
  int c0 = blockIdx.x * 32;
  int r0 = blockIdx.y * 32;
#pragma unroll
  for (int j = 0; j < 32; j += 8)
    tile[ty + j][tx] = W[(size_t)(r0 + ty + j) * 3072 + c0 + tx];
  __syncthreads();
#pragma unroll
  for (int j = 0; j < 32; j += 8)
    Wt[(size_t)(c0 + ty + j) * 1024 + r0 + tx] = f2bf(tile[tx][ty + j]);
}

// ---- GEMM 2048x3072 with fused prep epilogue ----
// outputs: qh[h][tok][e] bf16 (softmax(q)*0.125)
//          kh[h][tok][e] bf16 (exp(k))
//          kt[h][c][e][tok] bf16 (exp(k), transposed per chunk)
//          vt[h][c][e][tok] bf16 (v transposed per chunk)
__global__ __launch_bounds__(256) void k_gemm_fused(const unsigned short* __restrict__ xb,
                                                    const unsigned short* __restrict__ wt,
                                                    const float* __restrict__ bias,
                                                    unsigned short* __restrict__ qh,
                                                    unsigned short* __restrict__ kh,
                                                    unsigned short* __restrict__ kt,
                                                    unsigned short* __restrict__ vt) {
  __shared__ __align__(16) unsigned short As[128][32];
  __shared__ __align__(16) unsigned short Bs[128][32];
  const int t = threadIdx.x;
  const int lane = t & 63;
  const int wave = t >> 6;
  const int wr = wave >> 1, wc = wave & 1;
  const int rowBase = blockIdx.y * 128;
  const int colBase = blockIdx.x * 128;
  const int srow = t >> 2;
  const int scol = (t & 3) * 8;
  const unsigned short* ag = xb + (size_t)(rowBase + srow) * 1024 + scol;
  const unsigned short* bg = wt + (size_t)(colBase + srow) * 1024 + scol;
  unsigned short* al = &As[srow][scol];
  unsigned short* bl = &Bs[srow][scol];
  f32x4 acc[4][4] = {};
  const int fr = lane & 15;
  const int fk = (lane >> 4) * 8;
  for (int k0 = 0; k0 < 1024; k0 += 32) {
    __builtin_amdgcn_global_load_lds((const __attribute__((address_space(1))) void*)(ag + k0),
                                     (__attribute__((address_space(3))) void*)al, 16, 0, 0);
    __builtin_amdgcn_global_load_lds((const __attribute__((address_space(1))) void*)(ag + 64 * 1024 + k0),
                                     (__attribute__((address_space(3))) void*)(al + 64 * 32), 16, 0, 0);
    __builtin_amdgcn_global_load_lds((const __attribute__((address_space(1))) void*)(bg + k0),
                                     (__attribute__((address_space(3))) void*)bl, 16, 0, 0);
    __builtin_amdgcn_global_load_lds((const __attribute__((address_space(1))) void*)(bg + 64 * 1024 + k0),
                                     (__attribute__((address_space(3))) void*)(bl + 64 * 32), 16, 0, 0);
    __syncthreads();
    bf16x8 af[4], bfr[4];
#pragma unroll
    for (int m = 0; m < 4; ++m)
      af[m] = *(const bf16x8*)&As[wr * 64 + m * 16 + fr][fk];
#pragma unroll
    for (int n = 0; n < 4; ++n)
      bfr[n] = *(const bf16x8*)&Bs[wc * 64 + n * 16 + fr][fk];
#pragma unroll
    for (int m = 0; m < 4; ++m)
#pragma unroll
      for (int n = 0; n < 4; ++n)
        acc[m][n] = __builtin_amdgcn_mfma_f32_16x16x32_bf16(af[m], bfr[n], acc[m][n], 0, 0, 0);
    __syncthreads();
  }
  // ---- fused epilogue ----
  const int g = lane >> 4;            // C row group: row = 4g+i
  const int ocol = lane & 15;         // C col within 16-block
  const int col0 = colBase + wc * 64; // this wave's 64-col span = one head-region
  const int region = col0 >> 10;      // 0=q 1=v 2=k
  const int h = (col0 & 1023) >> 6;
  const int r0 = rowBase + wr * 64;   // token base (chunk-aligned)
  const int cch = r0 >> 6;            // chunk index
  float bv[4];
#pragma unroll
  for (int n = 0; n < 4; ++n) bv[n] = bias[col0 + 16 * n + ocol];

  if (region == 0) {                  // q: softmax over e (in-wave), *0.125
#pragma unroll
    for (int m = 0; m < 4; ++m) {
#pragma unroll
      for (int i = 0; i < 4; ++i) {
        float v[4];
#pragma unroll
        for (int n = 0; n < 4; ++n) v[n] = acc[m][n][i] + bv[n];
        float mx = fmaxf(fmaxf(v[0], v[1]), fmaxf(v[2], v[3]));
#pragma unroll
        for (int off = 1; off <= 8; off <<= 1) mx = fmaxf(mx, __shfl_xor(mx, off));
        float s = 0.f;
#pragma unroll
        for (int n = 0; n < 4; ++n) { v[n] = __expf(v[n] - mx); s += v[n]; }
#pragma unroll
        for (int off = 1; off <= 8; off <<= 1) s += __shfl_xor(s, off);
        float inv = 0.125f / s;
        int tok = r0 + 16 * m + 4 * g + i;
        unsigned short* qrow = qh + ((size_t)h * NTOK + tok) * 64;
#pragma unroll
        for (int n = 0; n < 4; ++n) qrow[16 * n + ocol] = f2bf(v[n] * inv);
      }
    }
  } else if (region == 1) {           // v: write transposed vt[h][c][e][tok]
    unsigned short* vb = vt + (size_t)(h * NCH + cch) * 4096;
#pragma unroll
    for (int m = 0; m < 4; ++m) {
      int tl = 16 * m + 4 * g;
#pragma unroll
      for (int n = 0; n < 4; ++n) {
        int e = 16 * n + ocol;
        ushort4 p = { f2bf(acc[m][n][0] + bv[n]), f2bf(acc[m][n][1] + bv[n]),
                      f2bf(acc[m][n][2] + bv[n]), f2bf(acc[m][n][3] + bv[n]) };
        *(ushort4*)&vb[(size_t)e * 64 + tl] = p;
      }
    }
  } else {                            // k: exp, write kh row-major + kt transposed
    unsigned short* kb = kt + (size_t)(h * NCH + cch) * 4096;
#pragma unroll
    for (int m = 0; m < 4; ++m) {
      int tl = 16 * m + 4 * g;
#pragma unroll
      for (int n = 0; n < 4; ++n) {
        int e = 16 * n + ocol;
        float kv[4];
#pragma unroll
        for (int i = 0; i < 4; ++i) kv[i] = __expf(acc[m][n][i] + bv[n]);
        ushort4 p = { f2bf(kv[0]), f2bf(kv[1]), f2bf(kv[2]), f2bf(kv[3]) };
        *(ushort4*)&kb[(size_t)e * 64 + tl] = p;
#pragma unroll
        for (int i = 0; i < 4; ++i)
          kh[((size_t)h * NTOK + r0 + tl + i) * 64 + e] = p[i];
      }
    }
  }
}

// ---- per-(h,c) chunk sums via MFMA: S[d][e'] = sum_i k[i][d] v[i][e'], stored as ScT[e'][d]; z[d] ----
__global__ __launch_bounds__(256) void k_chunk_sums(const unsigned short* __restrict__ kt,
                                                    const unsigned short* __restrict__ vt,
                                                    float* __restrict__ Sc,
                                                    float* __restrict__ zc) {
  int h = blockIdx.x >> 5, c = blockIdx.x & 31;
  __shared__ __align__(16) unsigned short Kt[64][72], Vt[64][72];
  int t = threadIdx.x, lane = t & 63, w = t >> 6;
  int fr = lane & 15, g = lane >> 4, fko = g * 8;
  const unsigned short* kg = kt + (size_t)(h * NCH + c) * 4096;
  const unsigned short* vg = vt + (size_t)(h * NCH + c) * 4096;
  for (int s = t; s < 512; s += 256) {
    int r = s >> 3, c8 = (s & 7) * 8;
    *(ushort8v*)&Kt[r][c8] = *(const ushort8v*)&kg[r * 64 + c8];
    *(ushort8v*)&Vt[r][c8] = *(const ushort8v*)&vg[r * 64 + c8];
  }
  __syncthreads();
  bf16x8 ka[2];
#pragma unroll
  for (int ks = 0; ks < 2; ++ks) ka[ks] = *(const bf16x8*)&Kt[16 * w + fr][32 * ks + fko];
  f32x4 s4[4] = {};
#pragma unroll
  for (int nb = 0; nb < 4; ++nb)
#pragma unroll
    for (int ks = 0; ks < 2; ++ks) {
      bf16x8 vf = *(const bf16x8*)&Vt[16 * nb + fr][32 * ks + fko];
      s4[nb] = __builtin_amdgcn_mfma_f32_16x16x32_bf16(ka[ks], vf, s4[nb], 0, 0, 0);
    }
  float* so = Sc + (size_t)(h * NCH + c) * 4096;   // [e'][d]
#pragma unroll
  for (int nb = 0; nb < 4; ++nb) {
    float4 o = { s4[nb][0], s4[nb][1], s4[nb][2], s4[nb][3] };  // d = 16w+4g+0..3
    *(float4*)&so[(size_t)(16 * nb + fr) * 64 + 16 * w + 4 * g] = o;
  }
  if (w == 0) {
    float z = 0.f;
#pragma unroll
    for (int j = 0; j < 8; ++j) {
      bf16x8 kv = *(const bf16x8*)&Kt[lane][j * 8];
#pragma unroll
      for (int e = 0; e < 8; ++e) z += bf2f((unsigned short)kv[e]);
    }
    zc[(size_t)(h * NCH + c) * 64 + lane] = z;
  }
}

// ---- exclusive prefix over chunks, fully element-parallel; S out as bf16 ----
__global__ __launch_bounds__(256) void k_scan(const float* __restrict__ Sc,
                                              unsigned short* __restrict__ Sp,
                                              const float* __restrict__ zc,
                                              float* __restrict__ zp) {
  int b = blockIdx.x;
  if (b < 256) {
    int tg = b * 256 + threadIdx.x;
    int h = tg >> 12, e = tg & 4095;
    float run = 0.f;
    for (int c = 0; c < NCH; ++c) {
      size_t idx = (size_t)(h * NCH + c) * 4096 + e;
      float v = Sc[idx];
      Sp[idx] = f2bf(run);
      run += v;
    }
  } else {
#pragma unroll
    for (int j = 0; j < 4; ++j) {
      int s = threadIdx.x + j * 256;
      int h = s >> 6, d = s & 63;
      float run = 0.f;
      for (int c = 0; c < NCH; ++c) {
        size_t idx = (size_t)(h * NCH + c) * 64 + d;
        zp[idx] = run;
        run += zc[idx];
      }
    }
  }
}

// ---- attention: O = M(QK^T) V + Q S_prev, denom fused; all MFMA ----
__global__ __launch_bounds__(256) void k_attn(const unsigned short* __restrict__ qh,
                                              const unsigned short* __restrict__ kh,
                                              const unsigned short* __restrict__ vt,
                                              const unsigned short* __restrict__ Sp,
                                              const float* __restrict__ zp,
                                              float* __restrict__ out) {
  int h = blockIdx.x >> 5, c = blockIdx.x & 31;
  __shared__ __align__(16) unsigned short Qs[64][72], Ks[64][72], Vts[64][72], Sts[64][72], Ams[64][72];
  __shared__ float zs[64], denom[64];
  int t = threadIdx.x, lane = t & 63, w = t >> 6;
  int fr = lane & 15, g = lane >> 4, fko = g * 8;
  const unsigned short* qg = qh + ((size_t)h * NTOK + c * 64) * 64;
  const unsigned short* kg = kh + ((size_t)h * NTOK + c * 64) * 64;
  const unsigned short* vg = vt + (size_t)(h * NCH + c) * 4096;
  const unsigned short* sg = Sp + (size_t)(h * NCH + c) * 4096;
  for (int s = t; s < 512; s += 256) {
    int r = s >> 3, c8 = (s & 7) * 8;
    *(ushort8v*)&Qs[r][c8]  = *(const ushort8v*)&qg[r * 64 + c8];
    *(ushort8v*)&Ks[r][c8]  = *(const ushort8v*)&kg[r * 64 + c8];
    *(ushort8v*)&Vts[r][c8] = *(const ushort8v*)&vg[r * 64 + c8];
    *(ushort8v*)&Sts[r][c8] = *(const ushort8v*)&sg[r * 64 + c8];
  }
  if (t < 64) zs[t] = zp[(size_t)(h * NCH + c) * 64 + t];
  __syncthreads();

  // step 1: A = Q K^T (wave w -> token rows 16w..16w+15)
  bf16x8 qa[2];
#pragma unroll
  for (int ks = 0; ks < 2; ++ks) qa[ks] = *(const bf16x8*)&Qs[16 * w + fr][32 * ks + fko];
  f32x4 a1[4] = {};
#pragma unroll
  for (int mb = 0; mb < 4; ++mb)
#pragma unroll
    for (int ks = 0; ks < 2; ++ks) {
      bf16x8 kf = *(const bf16x8*)&Ks[16 * mb + fr][32 * ks + fko];
      a1[mb] = __builtin_amdgcn_mfma_f32_16x16x32_bf16(qa[ks], kf, a1[mb], 0, 0, 0);
    }
  // mask, rowsum(+q·z_prev), write A to LDS bf16
#pragma unroll
  for (int i = 0; i < 4; ++i) {
    int n = 16 * w + 4 * g + i;
    float rs = 0.f;
#pragma unroll
    for (int j = 0; j < 4; ++j) rs += bf2f(Qs[n][fr * 4 + j]) * zs[fr * 4 + j];
#pragma unroll
    for (int mb = 0; mb < 4; ++mb) {
      int m = 16 * mb + fr;
      float v = (m <= n) ? a1[mb][i] : 0.f;
      a1[mb][i] = v;
      rs += v;
      Ams[n][16 * mb + fr] = f2bf(v);
    }
#pragma unroll
    for (int off = 1; off <= 8; off <<= 1) rs += __shfl_xor(rs, off);
    if (fr == 0) denom[n] = rs + 1.25e-7f;   // eps * sum(q) = 1e-6 * 0.125
  }
  __syncthreads();

  // step 2: O^T[e'][n] = Vt·A + St·Q  (wave w -> e' rows 16w..16w+15)
  bf16x8 xa[4];
#pragma unroll
  for (int ks = 0; ks < 2; ++ks) {
    xa[ks]     = *(const bf16x8*)&Vts[16 * w + fr][32 * ks + fko];
    xa[2 + ks] = *(const bf16x8*)&Sts[16 * w + fr][32 * ks + fko];
  }
  f32x4 o4[4] = {};
#pragma unroll
  for (int nb = 0; nb < 4; ++nb)
#pragma unroll
    for (int ks = 0; ks < 2; ++ks) {
      bf16x8 afr = *(const bf16x8*)&Ams[16 * nb + fr][32 * ks + fko];
      o4[nb] = __builtin_amdgcn_mfma_f32_16x16x32_bf16(xa[ks], afr, o4[nb], 0, 0, 0);
      bf16x8 qfr = *(const bf16x8*)&Qs[16 * nb + fr][32 * ks + fko];
      o4[nb] = __builtin_amdgcn_mfma_f32_16x16x32_bf16(xa[2 + ks], qfr, o4[nb], 0, 0, 0);
    }
#pragma unroll
  for (int nb = 0; nb < 4; ++nb) {
    int n = 16 * nb + fr;                       // token within chunk
    float dv = denom[n];
    float4 res = { o4[nb][0] / dv, o4[nb][1] / dv, o4[nb][2] / dv, o4[nb][3] / dv };
    *(float4*)&out[(size_t)(c * 64 + n) * 1024 + h * 64 + 16 * w + 4 * g] = res;
  }
}

extern "C" void kernel_launch(void* const* d_in, const int* in_sizes, int n_in,
                              void* d_out, int out_size, void* d_ws, size_t ws_size,
                              hipStream_t stream) {
  (void)in_sizes; (void)n_in; (void)out_size; (void)ws_size;
  const float* x = (const float*)d_in[0];
  const float* W = (const float*)d_in[1];
  const float* b = (const float*)d_in[2];
  char* ws = (char*)d_ws;

  const size_t MB = 1024 * 1024;
  unsigned short* xb = (unsigned short*)(ws + 0);        // 4 MB
  unsigned short* Wt = (unsigned short*)(ws + 4 * MB);   // 6 MB
  unsigned short* qh = (unsigned short*)(ws + 10 * MB);  // 4 MB
  unsigned short* kh = (unsigned short*)(ws + 14 * MB);  // 4 MB
  unsigned short* kt = (unsigned short*)(ws + 18 * MB);  // 4 MB
  unsigned short* vt = (unsigned short*)(ws + 22 * MB);  // 4 MB
  float*          Sc = (float*)(ws + 26 * MB);           // 8 MB
  unsigned short* Sp = (unsigned short*)(ws + 34 * MB);  // 4 MB
  float*          zc = (float*)(ws + 38 * MB);           // 128 KB
  float*          zp = (float*)(ws + 38 * MB + 131072);  // 128 KB

  k_convert_x<<<dim3(2048), dim3(256), 0, stream>>>(x, xb);
  k_transpose_w<<<dim3(96, 32), dim3(256), 0, stream>>>(W, Wt);
  k_gemm_fused<<<dim3(24, 16), dim3(256), 0, stream>>>(xb, Wt, b, qh, kh, kt, vt);
  k_chunk_sums<<<dim3(512), dim3(256), 0, stream>>>(kt, vt, Sc, zc);
  k_scan<<<dim3(257), dim3(256), 0, stream>>>(Sc, Sp, zc, zp);
  k_attn<<<dim3(512), dim3(256), 0, stream>>>(qh, kh, vt, Sp, zp, (float*)d_out);
}

// Round 3
// 59.718 us; speedup vs baseline: 2.1590x; 1.0273x over previous
//
#include <hip/hip_runtime.h>
#include <stdint.h>

// B=1, N=2048, D=1024, h=16, e=64; chunks of 64 tokens -> 32 chunks/head
#define NTOK 2048
#define NCH 32

typedef __attribute__((ext_vector_type(8))) short bf16x8;
typedef __attribute__((ext_vector_type(8))) unsigned short ushort8v;
typedef __attribute__((ext_vector_type(4))) float f32x4;

__device__ __forceinline__ unsigned short f2bf(float f) {
  unsigned u = __float_as_uint(f);
  u += 0x7fffu + ((u >> 16) & 1u);   // RNE
  return (unsigned short)(u >> 16);
}
__device__ __forceinline__ float bf2f(unsigned short s) {
  return __uint_as_float(((unsigned)s) << 16);
}

// ---- fused input prep: x -> bf16 (blocks 0..2047), W -> Wt bf16 transposed (blocks 2048..5119) ----
__global__ __launch_bounds__(256) void k_prep_inputs(const float* __restrict__ x,
                                                     unsigned short* __restrict__ xb,
                                                     const float* __restrict__ W,
                                                     unsigned short* __restrict__ Wt) {
  int bid = blockIdx.x;
  if (bid < 2048) {
    int i = (bid * 256 + threadIdx.x) * 4;
    float4 v = *(const float4*)(x + i);
    ushort4 o = { f2bf(v.x), f2bf(v.y), f2bf(v.z), f2bf(v.w) };
    *(ushort4*)(xb + i) = o;
  } else {
    __shared__ float tile[32][33];
    int id = bid - 2048;            // 3072 blocks: bx in [0,96), by in [0,32)
    int bx = id % 96, by = id / 96;
    int tx = threadIdx.x & 31, ty = threadIdx.x >> 5;
    int c0 = bx * 32;
    int r0 = by * 32;
#pragma unroll
    for (int j = 0; j < 32; j += 8)
      tile[ty + j][tx] = W[(size_t)(r0 + ty + j) * 3072 + c0 + tx];
    __syncthreads();
#pragma unroll
    for (int j = 0; j < 32; j += 8)
      Wt[(size_t)(c0 + ty + j) * 1024 + r0 + tx] = f2bf(tile[tx][ty + j]);
  }
}

// ---- GEMM 2048x3072, 128x128 tile, BK=64, double-buffered LDS (2-phase), XOR-swizzled ----
// fused prep epilogue:
//   qh[h][tok][e] bf16 (softmax(q)*0.125), kh[h][tok][e] bf16 (exp(k)),
//   kt[h][c][e][tok] bf16, vt[h][c][e][tok] bf16
__global__ __launch_bounds__(256) void k_gemm_fused(const unsigned short* __restrict__ xb,
                                                    const unsigned short* __restrict__ wt,
                                                    const float* __restrict__ bias,
                                                    unsigned short* __restrict__ qh,
                                                    unsigned short* __restrict__ kh,
                                                    unsigned short* __restrict__ kt,
                                                    unsigned short* __restrict__ vt) {
  __shared__ __align__(16) unsigned short As[2][128][64];
  __shared__ __align__(16) unsigned short Bs[2][128][64];
  const int t = threadIdx.x;
  const int lane = t & 63;
  const int wave = t >> 6;
  const int wr = wave >> 1, wc = wave & 1;
  const int rowBase = blockIdx.y * 128;
  const int colBase = blockIdx.x * 128;
  const int fr = lane & 15;
  const int khalf = lane >> 4;

  // staging geometry: thread t, instr i covers phys LDS bytes [i*4096 + t*16, +16)
  //   -> row = i*32 + (t>>3), phys slot = t&7; logical col slot = phys ^ (row&7)
  const int sr = t >> 3;
  const int ssl = (t & 7) ^ (sr & 7);   // i*32 == 0 (mod 8) so same for all i
  const unsigned short* agB = xb + (size_t)(rowBase + sr) * 1024 + ssl * 8;
  const unsigned short* bgB = wt + (size_t)(colBase + sr) * 1024 + ssl * 8;
  char* laB = (char*)&As[0][0][0] + t * 16;
  char* lbB = (char*)&Bs[0][0][0] + t * 16;

#define STG(b, kt0) do {                                                                  \
    const unsigned short* asrc_ = agB + (kt0) * 64;                                       \
    const unsigned short* bsrc_ = bgB + (kt0) * 64;                                       \
    char* la_ = laB + (b) * 16384;                                                        \
    char* lb_ = lbB + (b) * 16384;                                                        \
    _Pragma("unroll")                                                                     \
    for (int i_ = 0; i_ < 4; ++i_) {                                                      \
      __builtin_amdgcn_global_load_lds(                                                   \
          (const __attribute__((address_space(1))) void*)(asrc_ + i_ * 32768),            \
          (__attribute__((address_space(3))) void*)(la_ + i_ * 4096), 16, 0, 0);          \
      __builtin_amdgcn_global_load_lds(                                                   \
          (const __attribute__((address_space(1))) void*)(bsrc_ + i_ * 32768),            \
          (__attribute__((address_space(3))) void*)(lb_ + i_ * 4096), 16, 0, 0);          \
    }                                                                                     \
  } while (0)

  f32x4 acc[4][4] = {};
  const int fs0 = khalf ^ (fr & 7);   // swizzled slot for ks=0; ks=1 is fs0^4

  STG(0, 0);
  __syncthreads();
  int cur = 0;
#pragma unroll 1
  for (int ktile = 0; ktile < 15; ++ktile) {
    STG(cur ^ 1, ktile + 1);
    bf16x8 af[4][2], bff[4][2];
#pragma unroll
    for (int m = 0; m < 4; ++m) {
      const unsigned short* r = &As[cur][wr * 64 + m * 16 + fr][0];
      af[m][0] = *(const bf16x8*)(r + fs0 * 8);
      af[m][1] = *(const bf16x8*)(r + (fs0 ^ 4) * 8);
    }
#pragma unroll
    for (int n = 0; n < 4; ++n) {
      const unsigned short* r = &Bs[cur][wc * 64 + n * 16 + fr][0];
      bff[n][0] = *(const bf16x8*)(r + fs0 * 8);
      bff[n][1] = *(const bf16x8*)(r + (fs0 ^ 4) * 8);
    }
#pragma unroll
    for (int m = 0; m < 4; ++m)
#pragma unroll
      for (int n = 0; n < 4; ++n) {
        acc[m][n] = __builtin_amdgcn_mfma_f32_16x16x32_bf16(af[m][0], bff[n][0], acc[m][n], 0, 0, 0);
        acc[m][n] = __builtin_amdgcn_mfma_f32_16x16x32_bf16(af[m][1], bff[n][1], acc[m][n], 0, 0, 0);
      }
    __syncthreads();
    cur ^= 1;
  }
  {  // last K-tile
    bf16x8 af[4][2], bff[4][2];
#pragma unroll
    for (int m = 0; m < 4; ++m) {
      const unsigned short* r = &As[cur][wr * 64 + m * 16 + fr][0];
      af[m][0] = *(const bf16x8*)(r + fs0 * 8);
      af[m][1] = *(const bf16x8*)(r + (fs0 ^ 4) * 8);
    }
#pragma unroll
    for (int n = 0; n < 4; ++n) {
      const unsigned short* r = &Bs[cur][wc * 64 + n * 16 + fr][0];
      bff[n][0] = *(const bf16x8*)(r + fs0 * 8);
      bff[n][1] = *(const bf16x8*)(r + (fs0 ^ 4) * 8);
    }
#pragma unroll
    for (int m = 0; m < 4; ++m)
#pragma unroll
      for (int n = 0; n < 4; ++n) {
        acc[m][n] = __builtin_amdgcn_mfma_f32_16x16x32_bf16(af[m][0], bff[n][0], acc[m][n], 0, 0, 0);
        acc[m][n] = __builtin_amdgcn_mfma_f32_16x16x32_bf16(af[m][1], bff[n][1], acc[m][n], 0, 0, 0);
      }
  }
#undef STG

  // ---- fused epilogue (unchanged from R1) ----
  const int g = lane >> 4;            // C row group: row = 4g+i
  const int ocol = lane & 15;         // C col within 16-block
  const int col0 = colBase + wc * 64; // this wave's 64-col span = one head-region
  const int region = col0 >> 10;      // 0=q 1=v 2=k
  const int h = (col0 & 1023) >> 6;
  const int r0 = rowBase + wr * 64;   // token base (chunk-aligned)
  const int cch = r0 >> 6;            // chunk index
  float bv[4];
#pragma unroll
  for (int n = 0; n < 4; ++n) bv[n] = bias[col0 + 16 * n + ocol];

  if (region == 0) {                  // q: softmax over e (in-wave), *0.125
#pragma unroll
    for (int m = 0; m < 4; ++m) {
#pragma unroll
      for (int i = 0; i < 4; ++i) {
        float v[4];
#pragma unroll
        for (int n = 0; n < 4; ++n) v[n] = acc[m][n][i] + bv[n];
        float mx = fmaxf(fmaxf(v[0], v[1]), fmaxf(v[2], v[3]));
#pragma unroll
        for (int off = 1; off <= 8; off <<= 1) mx = fmaxf(mx, __shfl_xor(mx, off));
        float s = 0.f;
#pragma unroll
        for (int n = 0; n < 4; ++n) { v[n] = __expf(v[n] - mx); s += v[n]; }
#pragma unroll
        for (int off = 1; off <= 8; off <<= 1) s += __shfl_xor(s, off);
        float inv = 0.125f / s;
        int tok = r0 + 16 * m + 4 * g + i;
        unsigned short* qrow = qh + ((size_t)h * NTOK + tok) * 64;
#pragma unroll
        for (int n = 0; n < 4; ++n) qrow[16 * n + ocol] = f2bf(v[n] * inv);
      }
    }
  } else if (region == 1) {           // v: write transposed vt[h][c][e][tok]
    unsigned short* vb = vt + (size_t)(h * NCH + cch) * 4096;
#pragma unroll
    for (int m = 0; m < 4; ++m) {
      int tl = 16 * m + 4 * g;
#pragma unroll
      for (int n = 0; n < 4; ++n) {
        int e = 16 * n + ocol;
        ushort4 p = { f2bf(acc[m][n][0] + bv[n]), f2bf(acc[m][n][1] + bv[n]),
                      f2bf(acc[m][n][2] + bv[n]), f2bf(acc[m][n][3] + bv[n]) };
        *(ushort4*)&vb[(size_t)e * 64 + tl] = p;
      }
    }
  } else {                            // k: exp, write kh row-major + kt transposed
    unsigned short* kb = kt + (size_t)(h * NCH + cch) * 4096;
#pragma unroll
    for (int m = 0; m < 4; ++m) {
      int tl = 16 * m + 4 * g;
#pragma unroll
      for (int n = 0; n < 4; ++n) {
        int e = 16 * n + ocol;
        float kv[4];
#pragma unroll
        for (int i = 0; i < 4; ++i) kv[i] = __expf(acc[m][n][i] + bv[n]);
        ushort4 p = { f2bf(kv[0]), f2bf(kv[1]), f2bf(kv[2]), f2bf(kv[3]) };
        *(ushort4*)&kb[(size_t)e * 64 + tl] = p;
#pragma unroll
        for (int i = 0; i < 4; ++i)
          kh[((size_t)h * NTOK + r0 + tl + i) * 64 + e] = p[i];
      }
    }
  }
}

// ---- per-(h,c) chunk sums via MFMA: stored as ScT[e'][d]; z[d] ----
__global__ __launch_bounds__(256) void k_chunk_sums(const unsigned short* __restrict__ kt,
                                                    const unsigned short* __restrict__ vt,
                                                    float* __restrict__ Sc,
                                                    float* __restrict__ zc) {
  int h = blockIdx.x >> 5, c = blockIdx.x & 31;
  __shared__ __align__(16) unsigned short Kt[64][72], Vt[64][72];
  int t = threadIdx.x, lane = t & 63, w = t >> 6;
  int fr = lane & 15, g = lane >> 4, fko = g * 8;
  const unsigned short* kg = kt + (size_t)(h * NCH + c) * 4096;
  const unsigned short* vg = vt + (size_t)(h * NCH + c) * 4096;
  for (int s = t; s < 512; s += 256) {
    int r = s >> 3, c8 = (s & 7) * 8;
    *(ushort8v*)&Kt[r][c8] = *(const ushort8v*)&kg[r * 64 + c8];
    *(ushort8v*)&Vt[r][c8] = *(const ushort8v*)&vg[r * 64 + c8];
  }
  __syncthreads();
  bf16x8 ka[2];
#pragma unroll
  for (int ks = 0; ks < 2; ++ks) ka[ks] = *(const bf16x8*)&Kt[16 * w + fr][32 * ks + fko];
  f32x4 s4[4] = {};
#pragma unroll
  for (int nb = 0; nb < 4; ++nb)
#pragma unroll
    for (int ks = 0; ks < 2; ++ks) {
      bf16x8 vf = *(const bf16x8*)&Vt[16 * nb + fr][32 * ks + fko];
      s4[nb] = __builtin_amdgcn_mfma_f32_16x16x32_bf16(ka[ks], vf, s4[nb], 0, 0, 0);
    }
  float* so = Sc + (size_t)(h * NCH + c) * 4096;   // [e'][d]
#pragma unroll
  for (int nb = 0; nb < 4; ++nb) {
    float4 o = { s4[nb][0], s4[nb][1], s4[nb][2], s4[nb][3] };
    *(float4*)&so[(size_t)(16 * nb + fr) * 64 + 16 * w + 4 * g] = o;
  }
  if (w == 0) {
    float z = 0.f;
#pragma unroll
    for (int j = 0; j < 8; ++j) {
      bf16x8 kv = *(const bf16x8*)&Kt[lane][j * 8];
#pragma unroll
      for (int e = 0; e < 8; ++e) z += bf2f((unsigned short)kv[e]);
    }
    zc[(size_t)(h * NCH + c) * 64 + lane] = z;
  }
}

// ---- exclusive prefix over chunks, element-parallel; S out as bf16 ----
__global__ __launch_bounds__(256) void k_scan(const float* __restrict__ Sc,
                                              unsigned short* __restrict__ Sp,
                                              const float* __restrict__ zc,
                                              float* __restrict__ zp) {
  int b = blockIdx.x;
  if (b < 256) {
    int tg = b * 256 + threadIdx.x;
    int h = tg >> 12, e = tg & 4095;
    float run = 0.f;
    for (int c = 0; c < NCH; ++c) {
      size_t idx = (size_t)(h * NCH + c) * 4096 + e;
      float v = Sc[idx];
      Sp[idx] = f2bf(run);
      run += v;
    }
  } else {
#pragma unroll
    for (int j = 0; j < 4; ++j) {
      int s = threadIdx.x + j * 256;
      int h = s >> 6, d = s & 63;
      float run = 0.f;
      for (int c = 0; c < NCH; ++c) {
        size_t idx = (size_t)(h * NCH + c) * 64 + d;
        zp[idx] = run;
        run += zc[idx];
      }
    }
  }
}

// ---- attention: O = M(QK^T) V + Q S_prev, denom fused; all MFMA ----
__global__ __launch_bounds__(256) void k_attn(const unsigned short* __restrict__ qh,
                                              const unsigned short* __restrict__ kh,
                                              const unsigned short* __restrict__ vt,
                                              const unsigned short* __restrict__ Sp,
                                              const float* __restrict__ zp,
                                              float* __restrict__ out) {
  int h = blockIdx.x >> 5, c = blockIdx.x & 31;
  __shared__ __align__(16) unsigned short Qs[64][72], Ks[64][72], Vts[64][72], Sts[64][72], Ams[64][72];
  __shared__ float zs[64], denom[64];
  int t = threadIdx.x, lane = t & 63, w = t >> 6;
  int fr = lane & 15, g = lane >> 4, fko = g * 8;
  const unsigned short* qg = qh + ((size_t)h * NTOK + c * 64) * 64;
  const unsigned short* kg = kh + ((size_t)h * NTOK + c * 64) * 64;
  const unsigned short* vg = vt + (size_t)(h * NCH + c) * 4096;
  const unsigned short* sg = Sp + (size_t)(h * NCH + c) * 4096;
  for (int s = t; s < 512; s += 256) {
    int r = s >> 3, c8 = (s & 7) * 8;
    *(ushort8v*)&Qs[r][c8]  = *(const ushort8v*)&qg[r * 64 + c8];
    *(ushort8v*)&Ks[r][c8]  = *(const ushort8v*)&kg[r * 64 + c8];
    *(ushort8v*)&Vts[r][c8] = *(const ushort8v*)&vg[r * 64 + c8];
    *(ushort8v*)&Sts[r][c8] = *(const ushort8v*)&sg[r * 64 + c8];
  }
  if (t < 64) zs[t] = zp[(size_t)(h * NCH + c) * 64 + t];
  __syncthreads();

  // step 1: A = Q K^T
  bf16x8 qa[2];
#pragma unroll
  for (int ks = 0; ks < 2; ++ks) qa[ks] = *(const bf16x8*)&Qs[16 * w + fr][32 * ks + fko];
  f32x4 a1[4] = {};
#pragma unroll
  for (int mb = 0; mb < 4; ++mb)
#pragma unroll
    for (int ks = 0; ks < 2; ++ks) {
      bf16x8 kf = *(const bf16x8*)&Ks[16 * mb + fr][32 * ks + fko];
      a1[mb] = __builtin_amdgcn_mfma_f32_16x16x32_bf16(qa[ks], kf, a1[mb], 0, 0, 0);
    }
#pragma unroll
  for (int i = 0; i < 4; ++i) {
    int n = 16 * w + 4 * g + i;
    float rs = 0.f;
#pragma unroll
    for (int j = 0; j < 4; ++j) rs += bf2f(Qs[n][fr * 4 + j]) * zs[fr * 4 + j];
#pragma unroll
    for (int mb = 0; mb < 4; ++mb) {
      int m = 16 * mb + fr;
      float v = (m <= n) ? a1[mb][i] : 0.f;
      a1[mb][i] = v;
      rs += v;
      Ams[n][16 * mb + fr] = f2bf(v);
    }
#pragma unroll
    for (int off = 1; off <= 8; off <<= 1) rs += __shfl_xor(rs, off);
    if (fr == 0) denom[n] = rs + 1.25e-7f;   // eps * sum(q) = 1e-6 * 0.125
  }
  __syncthreads();

  // step 2: O^T[e'][n] = Vt·A + St·Q
  bf16x8 xa[4];
#pragma unroll
  for (int ks = 0; ks < 2; ++ks) {
    xa[ks]     = *(const bf16x8*)&Vts[16 * w + fr][32 * ks + fko];
    xa[2 + ks] = *(const bf16x8*)&Sts[16 * w + fr][32 * ks + fko];
  }
  f32x4 o4[4] = {};
#pragma unroll
  for (int nb = 0; nb < 4; ++nb)
#pragma unroll
    for (int ks = 0; ks < 2; ++ks) {
      bf16x8 afr = *(const bf16x8*)&Ams[16 * nb + fr][32 * ks + fko];
      o4[nb] = __builtin_amdgcn_mfma_f32_16x16x32_bf16(xa[ks], afr, o4[nb], 0, 0, 0);
      bf16x8 qfr = *(const bf16x8*)&Qs[16 * nb + fr][32 * ks + fko];
      o4[nb] = __builtin_amdgcn_mfma_f32_16x16x32_bf16(xa[2 + ks], qfr, o4[nb], 0, 0, 0);
    }
#pragma unroll
  for (int nb = 0; nb < 4; ++nb) {
    int n = 16 * nb + fr;
    float dv = denom[n];
    float4 res = { o4[nb][0] / dv, o4[nb][1] / dv, o4[nb][2] / dv, o4[nb][3] / dv };
    *(float4*)&out[(size_t)(c * 64 + n) * 1024 + h * 64 + 16 * w + 4 * g] = res;
  }
}

extern "C" void kernel_launch(void* const* d_in, const int* in_sizes, int n_in,
                              void* d_out, int out_size, void* d_ws, size_t ws_size,
                              hipStream_t stream) {
  (void)in_sizes; (void)n_in; (void)out_size; (void)ws_size;
  const float* x = (const float*)d_in[0];
  const float* W = (const float*)d_in[1];
  const float* b = (const float*)d_in[2];
  char* ws = (char*)d_ws;

  const size_t MB = 1024 * 1024;
  unsigned short* xb = (unsigned short*)(ws + 0);        // 4 MB
  unsigned short* Wt = (unsigned short*)(ws + 4 * MB);   // 6 MB
  unsigned short* qh = (unsigned short*)(ws + 10 * MB);  // 4 MB
  unsigned short* kh = (unsigned short*)(ws + 14 * MB);  // 4 MB
  unsigned short* kt = (unsigned short*)(ws + 18 * MB);  // 4 MB
  unsigned short* vt = (unsigned short*)(ws + 22 * MB);  // 4 MB
  float*          Sc = (float*)(ws + 26 * MB);           // 8 MB
  unsigned short* Sp = (unsigned short*)(ws + 34 * MB);  // 4 MB
  float*          zc = (float*)(ws + 38 * MB);           // 128 KB
  float*          zp = (float*)(ws + 38 * MB + 131072);  // 128 KB

  k_prep_inputs<<<dim3(5120), dim3(256), 0, stream>>>(x, xb, W, Wt);
  k_gemm_fused<<<dim3(24, 16), dim3(256), 0, stream>>>(xb, Wt, b, qh, kh, kt, vt);
  k_chunk_sums<<<dim3(512), dim3(256), 0, stream>>>(kt, vt, Sc, zc);
  k_scan<<<dim3(257), dim3(256), 0, stream>>>(Sc, Sp, zc, zp);
  k_attn<<<dim3(512), dim3(256), 0, stream>>>(qh, kh, vt, Sp, zp, (float*)d_out);
}

// Round 4
// 49.723 us; speedup vs baseline: 2.5929x; 1.2010x over previous
//
#include <hip/hip_runtime.h>
#include <stdint.h>

// B=1, N=2048, D=1024, h=16, e=64; chunks of 64 tokens -> 32 chunks/head
#define NTOK 2048
#define NCH 32

typedef __attribute__((ext_vector_type(8))) short bf16x8;
typedef __attribute__((ext_vector_type(8))) unsigned short ushort8v;
typedef __attribute__((ext_vector_type(4))) float f32x4;

__device__ __forceinline__ unsigned short f2bf(float f) {
  unsigned u = __float_as_uint(f);
  u += 0x7fffu + ((u >> 16) & 1u);   // RNE
  return (unsigned short)(u >> 16);
}
__device__ __forceinline__ float bf2f(unsigned short s) {
  return __uint_as_float(((unsigned)s) << 16);
}

// ---- fused input prep: x -> bf16 (blocks 0..2047), W -> Wt bf16 transposed (blocks 2048..5119) ----
__global__ __launch_bounds__(256) void k_prep_inputs(const float* __restrict__ x,
                                                     unsigned short* __restrict__ xb,
                                                     const float* __restrict__ W,
                                                     unsigned short* __restrict__ Wt) {
  int bid = blockIdx.x;
  if (bid < 2048) {
    int i = (bid * 256 + threadIdx.x) * 4;
    float4 v = *(const float4*)(x + i);
    ushort4 o = { f2bf(v.x), f2bf(v.y), f2bf(v.z), f2bf(v.w) };
    *(ushort4*)(xb + i) = o;
  } else {
    __shared__ float tile[32][33];
    int id = bid - 2048;            // 3072 blocks: bx in [0,96), by in [0,32)
    int bx = id % 96, by = id / 96;
    int tx = threadIdx.x & 31, ty = threadIdx.x >> 5;
    int c0 = bx * 32;
    int r0 = by * 32;
#pragma unroll
    for (int j = 0; j < 32; j += 8)
      tile[ty + j][tx] = W[(size_t)(r0 + ty + j) * 3072 + c0 + tx];
    __syncthreads();
#pragma unroll
    for (int j = 0; j < 32; j += 8)
      Wt[(size_t)(c0 + ty + j) * 1024 + r0 + tx] = f2bf(tile[tx][ty + j]);
  }
}

// ---- GEMM 2048x3072, 128x128 tile, 8 waves (512 thr), BK=64, dbuf, XOR-swizzled ----
// wave w: rows wr*32..+31 (wr=w>>1), cols wc*64..+63 (wc=w&1) -> one head region per wave
// fused prep epilogue:
//   qh[h][tok][e] bf16 (softmax(q)*0.125), kh[h][tok][e] bf16 (exp(k)),
//   kt[h][c][e][tok] bf16, vt[h][c][e][tok] bf16
__global__ __launch_bounds__(512) void k_gemm_fused(const unsigned short* __restrict__ xb,
                                                    const unsigned short* __restrict__ wt,
                                                    const float* __restrict__ bias,
                                                    unsigned short* __restrict__ qh,
                                                    unsigned short* __restrict__ kh,
                                                    unsigned short* __restrict__ kt,
                                                    unsigned short* __restrict__ vt) {
  __shared__ __align__(16) unsigned short As[2][128][64];
  __shared__ __align__(16) unsigned short Bs[2][128][64];
  const int t = threadIdx.x;           // 0..511
  const int lane = t & 63;
  const int wave = t >> 6;             // 0..7
  const int wr = wave >> 1;            // 0..3 (32-row block)
  const int wc = wave & 1;             // 0..1 (64-col block)
  const int rowBase = blockIdx.y * 128;
  const int colBase = blockIdx.x * 128;
  const int fr = lane & 15;
  const int khalf = lane >> 4;         // 0..3

  // staging: thread t, instr i covers phys LDS bytes [i*8192 + t*16, +16)
  //   row = i*64 + (t>>3), phys slot = t&7; logical slot = phys ^ (row&7)
  const int sr = t >> 3;               // 0..63
  const int ssl = (t & 7) ^ (sr & 7);  // i*64 == 0 (mod 8) -> same for both i
  const unsigned short* agB = xb + (size_t)(rowBase + sr) * 1024 + ssl * 8;
  const unsigned short* bgB = wt + (size_t)(colBase + sr) * 1024 + ssl * 8;
  char* laB = (char*)As + t * 16;
  char* lbB = (char*)Bs + t * 16;

#define STG(b, kt0) do {                                                                  \
    _Pragma("unroll")                                                                     \
    for (int i_ = 0; i_ < 2; ++i_) {                                                      \
      __builtin_amdgcn_global_load_lds(                                                   \
          (const __attribute__((address_space(1))) void*)(agB + (kt0) * 64 + i_ * 65536), \
          (__attribute__((address_space(3))) void*)(laB + (b) * 16384 + i_ * 8192), 16, 0, 0); \
      __builtin_amdgcn_global_load_lds(                                                   \
          (const __attribute__((address_space(1))) void*)(bgB + (kt0) * 64 + i_ * 65536), \
          (__attribute__((address_space(3))) void*)(lbB + (b) * 16384 + i_ * 8192), 16, 0, 0); \
    }                                                                                     \
  } while (0)

  f32x4 acc[2][4] = {};
  const int fs0 = khalf ^ (fr & 7);   // physical slot for ks=0; ks=1 is fs0^4

#define FRAGS_MFMA(cur) do {                                                              \
    bf16x8 af[2][2], bff[4][2];                                                           \
    _Pragma("unroll")                                                                     \
    for (int m = 0; m < 2; ++m) {                                                         \
      const unsigned short* r = &As[cur][wr * 32 + m * 16 + fr][0];                       \
      af[m][0] = *(const bf16x8*)(r + fs0 * 8);                                           \
      af[m][1] = *(const bf16x8*)(r + (fs0 ^ 4) * 8);                                     \
    }                                                                                     \
    _Pragma("unroll")                                                                     \
    for (int n = 0; n < 4; ++n) {                                                         \
      const unsigned short* r = &Bs[cur][wc * 64 + n * 16 + fr][0];                       \
      bff[n][0] = *(const bf16x8*)(r + fs0 * 8);                                          \
      bff[n][1] = *(const bf16x8*)(r + (fs0 ^ 4) * 8);                                    \
    }                                                                                     \
    _Pragma("unroll")                                                                     \
    for (int m = 0; m < 2; ++m)                                                           \
      _Pragma("unroll")                                                                   \
      for (int n = 0; n < 4; ++n) {                                                       \
        acc[m][n] = __builtin_amdgcn_mfma_f32_16x16x32_bf16(af[m][0], bff[n][0], acc[m][n], 0, 0, 0); \
        acc[m][n] = __builtin_amdgcn_mfma_f32_16x16x32_bf16(af[m][1], bff[n][1], acc[m][n], 0, 0, 0); \
      }                                                                                   \
  } while (0)

  STG(0, 0);
  __syncthreads();
  int cur = 0;
#pragma unroll 1
  for (int ktile = 0; ktile < 15; ++ktile) {
    STG(cur ^ 1, ktile + 1);
    FRAGS_MFMA(cur);
    __syncthreads();
    cur ^= 1;
  }
  FRAGS_MFMA(cur);
#undef STG
#undef FRAGS_MFMA

  // ---- fused epilogue ----
  const int g = khalf;                // C row group: row = 4g+i (g = lane>>4, 0..3)
  const int ocol = lane & 15;         // C col within 16-block
  const int col0 = colBase + wc * 64; // this wave's 64-col span = one head-region
  const int region = col0 >> 10;      // 0=q 1=v 2=k
  const int h = (col0 & 1023) >> 6;
  const int r0 = rowBase + wr * 32;   // global token base of this wave
  const int cch = r0 >> 6;            // chunk index
  const int lbase = (wr & 1) * 32;    // chunk-local row base
  float bv[4];
#pragma unroll
  for (int n = 0; n < 4; ++n) bv[n] = bias[col0 + 16 * n + ocol];

  if (region == 0) {                  // q: softmax over e (in-wave), *0.125
#pragma unroll
    for (int m = 0; m < 2; ++m) {
#pragma unroll
      for (int i = 0; i < 4; ++i) {
        float v[4];
#pragma unroll
        for (int n = 0; n < 4; ++n) v[n] = acc[m][n][i] + bv[n];
        float mx = fmaxf(fmaxf(v[0], v[1]), fmaxf(v[2], v[3]));
#pragma unroll
        for (int off = 1; off <= 8; off <<= 1) mx = fmaxf(mx, __shfl_xor(mx, off));
        float s = 0.f;
#pragma unroll
        for (int n = 0; n < 4; ++n) { v[n] = __expf(v[n] - mx); s += v[n]; }
#pragma unroll
        for (int off = 1; off <= 8; off <<= 1) s += __shfl_xor(s, off);
        float inv = 0.125f / s;
        int tok = r0 + 16 * m + 4 * g + i;
        unsigned short* qrow = qh + ((size_t)h * NTOK + tok) * 64;
#pragma unroll
        for (int n = 0; n < 4; ++n) qrow[16 * n + ocol] = f2bf(v[n] * inv);
      }
    }
  } else if (region == 1) {           // v: write transposed vt[h][c][e][tok]
    unsigned short* vb = vt + (size_t)(h * NCH + cch) * 4096;
#pragma unroll
    for (int m = 0; m < 2; ++m) {
      int tl = lbase + 16 * m + 4 * g;
#pragma unroll
      for (int n = 0; n < 4; ++n) {
        int e = 16 * n + ocol;
        ushort4 p = { f2bf(acc[m][n][0] + bv[n]), f2bf(acc[m][n][1] + bv[n]),
                      f2bf(acc[m][n][2] + bv[n]), f2bf(acc[m][n][3] + bv[n]) };
        *(ushort4*)&vb[(size_t)e * 64 + tl] = p;
      }
    }
  } else {                            // k: exp, write kh row-major + kt transposed
    unsigned short* kb = kt + (size_t)(h * NCH + cch) * 4096;
#pragma unroll
    for (int m = 0; m < 2; ++m) {
      int tl = lbase + 16 * m + 4 * g;
#pragma unroll
      for (int n = 0; n < 4; ++n) {
        int e = 16 * n + ocol;
        float kv[4];
#pragma unroll
        for (int i = 0; i < 4; ++i) kv[i] = __expf(acc[m][n][i] + bv[n]);
        ushort4 p = { f2bf(kv[0]), f2bf(kv[1]), f2bf(kv[2]), f2bf(kv[3]) };
        *(ushort4*)&kb[(size_t)e * 64 + tl] = p;
#pragma unroll
        for (int i = 0; i < 4; ++i)
          kh[((size_t)h * NTOK + r0 + 16 * m + 4 * g + i) * 64 + e] = p[i];
      }
    }
  }
}

// ---- per-(h,c) chunk sums via MFMA: stored as ScT[e'][d]; z[d] ----
__global__ __launch_bounds__(256) void k_chunk_sums(const unsigned short* __restrict__ kt,
                                                    const unsigned short* __restrict__ vt,
                                                    float* __restrict__ Sc,
                                                    float* __restrict__ zc) {
  int h = blockIdx.x >> 5, c = blockIdx.x & 31;
  __shared__ __align__(16) unsigned short Kt[64][72], Vt[64][72];
  int t = threadIdx.x, lane = t & 63, w = t >> 6;
  int fr = lane & 15, g = lane >> 4, fko = g * 8;
  const unsigned short* kg = kt + (size_t)(h * NCH + c) * 4096;
  const unsigned short* vg = vt + (size_t)(h * NCH + c) * 4096;
  for (int s = t; s < 512; s += 256) {
    int r = s >> 3, c8 = (s & 7) * 8;
    *(ushort8v*)&Kt[r][c8] = *(const ushort8v*)&kg[r * 64 + c8];
    *(ushort8v*)&Vt[r][c8] = *(const ushort8v*)&vg[r * 64 + c8];
  }
  __syncthreads();
  bf16x8 ka[2];
#pragma unroll
  for (int ks = 0; ks < 2; ++ks) ka[ks] = *(const bf16x8*)&Kt[16 * w + fr][32 * ks + fko];
  f32x4 s4[4] = {};
#pragma unroll
  for (int nb = 0; nb < 4; ++nb)
#pragma unroll
    for (int ks = 0; ks < 2; ++ks) {
      bf16x8 vf = *(const bf16x8*)&Vt[16 * nb + fr][32 * ks + fko];
      s4[nb] = __builtin_amdgcn_mfma_f32_16x16x32_bf16(ka[ks], vf, s4[nb], 0, 0, 0);
    }
  float* so = Sc + (size_t)(h * NCH + c) * 4096;   // [e'][d]
#pragma unroll
  for (int nb = 0; nb < 4; ++nb) {
    float4 o = { s4[nb][0], s4[nb][1], s4[nb][2], s4[nb][3] };
    *(float4*)&so[(size_t)(16 * nb + fr) * 64 + 16 * w + 4 * g] = o;
  }
  if (w == 0) {
    float z = 0.f;
#pragma unroll
    for (int j = 0; j < 8; ++j) {
      bf16x8 kv = *(const bf16x8*)&Kt[lane][j * 8];
#pragma unroll
      for (int e = 0; e < 8; ++e) z += bf2f((unsigned short)kv[e]);
    }
    zc[(size_t)(h * NCH + c) * 64 + lane] = z;
  }
}

// ---- exclusive prefix over chunks, element-parallel; S out as bf16 ----
__global__ __launch_bounds__(256) void k_scan(const float* __restrict__ Sc,
                                              unsigned short* __restrict__ Sp,
                                              const float* __restrict__ zc,
                                              float* __restrict__ zp) {
  int b = blockIdx.x;
  if (b < 256) {
    int tg = b * 256 + threadIdx.x;
    int h = tg >> 12, e = tg & 4095;
    float run = 0.f;
    for (int c = 0; c < NCH; ++c) {
      size_t idx = (size_t)(h * NCH + c) * 4096 + e;
      float v = Sc[idx];
      Sp[idx] = f2bf(run);
      run += v;
    }
  } else {
#pragma unroll
    for (int j = 0; j < 4; ++j) {
      int s = threadIdx.x + j * 256;
      int h = s >> 6, d = s & 63;
      float run = 0.f;
      for (int c = 0; c < NCH; ++c) {
        size_t idx = (size_t)(h * NCH + c) * 64 + d;
        zp[idx] = run;
        run += zc[idx];
      }
    }
  }
}

// ---- attention: O = M(QK^T) V + Q S_prev, denom fused; all MFMA ----
__global__ __launch_bounds__(256) void k_attn(const unsigned short* __restrict__ qh,
                                              const unsigned short* __restrict__ kh,
                                              const unsigned short* __restrict__ vt,
                                              const unsigned short* __restrict__ Sp,
                                              const float* __restrict__ zp,
                                              float* __restrict__ out) {
  int h = blockIdx.x >> 5, c = blockIdx.x & 31;
  __shared__ __align__(16) unsigned short Qs[64][72], Ks[64][72], Vts[64][72], Sts[64][72], Ams[64][72];
  __shared__ float zs[64], denom[64];
  int t = threadIdx.x, lane = t & 63, w = t >> 6;
  int fr = lane & 15, g = lane >> 4, fko = g * 8;
  const unsigned short* qg = qh + ((size_t)h * NTOK + c * 64) * 64;
  const unsigned short* kg = kh + ((size_t)h * NTOK + c * 64) * 64;
  const unsigned short* vg = vt + (size_t)(h * NCH + c) * 4096;
  const unsigned short* sg = Sp + (size_t)(h * NCH + c) * 4096;
  for (int s = t; s < 512; s += 256) {
    int r = s >> 3, c8 = (s & 7) * 8;
    *(ushort8v*)&Qs[r][c8]  = *(const ushort8v*)&qg[r * 64 + c8];
    *(ushort8v*)&Ks[r][c8]  = *(const ushort8v*)&kg[r * 64 + c8];
    *(ushort8v*)&Vts[r][c8] = *(const ushort8v*)&vg[r * 64 + c8];
    *(ushort8v*)&Sts[r][c8] = *(const ushort8v*)&sg[r * 64 + c8];
  }
  if (t < 64) zs[t] = zp[(size_t)(h * NCH + c) * 64 + t];
  __syncthreads();

  // step 1: A = Q K^T
  bf16x8 qa[2];
#pragma unroll
  for (int ks = 0; ks < 2; ++ks) qa[ks] = *(const bf16x8*)&Qs[16 * w + fr][32 * ks + fko];
  f32x4 a1[4] = {};
#pragma unroll
  for (int mb = 0; mb < 4; ++mb)
#pragma unroll
    for (int ks = 0; ks < 2; ++ks) {
      bf16x8 kf = *(const bf16x8*)&Ks[16 * mb + fr][32 * ks + fko];
      a1[mb] = __builtin_amdgcn_mfma_f32_16x16x32_bf16(qa[ks], kf, a1[mb], 0, 0, 0);
    }
#pragma unroll
  for (int i = 0; i < 4; ++i) {
    int n = 16 * w + 4 * g + i;
    float rs = 0.f;
#pragma unroll
    for (int j = 0; j < 4; ++j) rs += bf2f(Qs[n][fr * 4 + j]) * zs[fr * 4 + j];
#pragma unroll
    for (int mb = 0; mb < 4; ++mb) {
      int m = 16 * mb + fr;
      float v = (m <= n) ? a1[mb][i] : 0.f;
      a1[mb][i] = v;
      rs += v;
      Ams[n][16 * mb + fr] = f2bf(v);
    }
#pragma unroll
    for (int off = 1; off <= 8; off <<= 1) rs += __shfl_xor(rs, off);
    if (fr == 0) denom[n] = rs + 1.25e-7f;   // eps * sum(q) = 1e-6 * 0.125
  }
  __syncthreads();

  // step 2: O^T[e'][n] = Vt·A + St·Q
  bf16x8 xa[4];
#pragma unroll
  for (int ks = 0; ks < 2; ++ks) {
    xa[ks]     = *(const bf16x8*)&Vts[16 * w + fr][32 * ks + fko];
    xa[2 + ks] = *(const bf16x8*)&Sts[16 * w + fr][32 * ks + fko];
  }
  f32x4 o4[4] = {};
#pragma unroll
  for (int nb = 0; nb < 4; ++nb)
#pragma unroll
    for (int ks = 0; ks < 2; ++ks) {
      bf16x8 afr = *(const bf16x8*)&Ams[16 * nb + fr][32 * ks + fko];
      o4[nb] = __builtin_amdgcn_mfma_f32_16x16x32_bf16(xa[ks], afr, o4[nb], 0, 0, 0);
      bf16x8 qfr = *(const bf16x8*)&Qs[16 * nb + fr][32 * ks + fko];
      o4[nb] = __builtin_amdgcn_mfma_f32_16x16x32_bf16(xa[2 + ks], qfr, o4[nb], 0, 0, 0);
    }
#pragma unroll
  for (int nb = 0; nb < 4; ++nb) {
    int n = 16 * nb + fr;
    float dv = denom[n];
    float4 res = { o4[nb][0] / dv, o4[nb][1] / dv, o4[nb][2] / dv, o4[nb][3] / dv };
    *(float4*)&out[(size_t)(c * 64 + n) * 1024 + h * 64 + 16 * w + 4 * g] = res;
  }
}

extern "C" void kernel_launch(void* const* d_in, const int* in_sizes, int n_in,
                              void* d_out, int out_size, void* d_ws, size_t ws_size,
                              hipStream_t stream) {
  (void)in_sizes; (void)n_in; (void)out_size; (void)ws_size;
  const float* x = (const float*)d_in[0];
  const float* W = (const float*)d_in[1];
  const float* b = (const float*)d_in[2];
  char* ws = (char*)d_ws;

  const size_t MB = 1024 * 1024;
  unsigned short* xb = (unsigned short*)(ws + 0);        // 4 MB
  unsigned short* Wt = (unsigned short*)(ws + 4 * MB);   // 6 MB
  unsigned short* qh = (unsigned short*)(ws + 10 * MB);  // 4 MB
  unsigned short* kh = (unsigned short*)(ws + 14 * MB);  // 4 MB
  unsigned short* kt = (unsigned short*)(ws + 18 * MB);  // 4 MB
  unsigned short* vt = (unsigned short*)(ws + 22 * MB);  // 4 MB
  float*          Sc = (float*)(ws + 26 * MB);           // 8 MB
  unsigned short* Sp = (unsigned short*)(ws + 34 * MB);  // 4 MB
  float*          zc = (float*)(ws + 38 * MB);           // 128 KB
  float*          zp = (float*)(ws + 38 * MB + 131072);  // 128 KB

  k_prep_inputs<<<dim3(5120), dim3(256), 0, stream>>>(x, xb, W, Wt);
  k_gemm_fused<<<dim3(24, 16), dim3(512), 0, stream>>>(xb, Wt, b, qh, kh, kt, vt);
  k_chunk_sums<<<dim3(512), dim3(256), 0, stream>>>(kt, vt, Sc, zc);
  k_scan<<<dim3(257), dim3(256), 0, stream>>>(Sc, Sp, zc, zp);
  k_attn<<<dim3(512), dim3(256), 0, stream>>>(qh, kh, vt, Sp, zp, (float*)d_out);
}